// Round 3
// baseline (216.192 us; speedup 1.0000x reference)
//
#include <hip/hip_runtime.h>
#include <hip/hip_bf16.h>

// Problem dims (fixed by reference setup_inputs)
#define M_DIM 32
#define K_DIM 8192
#define N_DIM 8192
#define KS 8                         // k-split slices (atomic adds per output elem)
#define KCH (K_DIM / KS)             // 1024 k per block
#define CHK 128                      // k per pipelined chunk
#define NCHK (KCH / CHK)             // 8 chunks
#define STEPS (CHK / 32)             // 4 MFMA k-steps per chunk
#define NPB 64                       // n-cols per block
#define MAIN_BLOCKS ((N_DIM / NPB) * KS)  // 1024

#define QW_ROWI4 (K_DIM / 8)         // 1024 int4 per qweight row
#define SC_ROW (K_DIM / 16)          // 512 f32 per scales row

// LDS strides (padding class proven earlier; conflicts <=2-way = free)
#define QROW 17                      // packed dwords per Q row (16 + 1)
#define AROW 136                     // f16 per A row (128 + 8)
#define SROW 9                       // f32 per S row (8 + 1)

typedef _Float16 half8   __attribute__((ext_vector_type(8)));
typedef _Float16 half4_t __attribute__((ext_vector_type(4)));
typedef float    floatx4 __attribute__((ext_vector_type(4)));
typedef float    floatx2 __attribute__((ext_vector_type(2)));

// ---- Proven E2M1 bit-decode (absmax 2.0 pedigree) ----
__device__ __forceinline__ uint32_t dec2(uint32_t b) {
  uint32_t c0 = b & 0xFu, c1 = (b >> 4) & 0xFu;
  uint32_t m0 = c0 & 7u, m1 = c1 & 7u;
  uint32_t t0 = min(28u * m0, m0 + 28u);
  uint32_t t1 = min(28u * m1, m1 + 28u);
  return (t0 << 9) | ((c0 & 8u) << 12)
       | (t1 << 25) | ((c1 & 8u) << 28);
}

// Packed dword (4 payload bytes = 8 fp4 along k) -> 8 f16, times f16 scale.
__device__ __forceinline__ half8 decode8p(uint32_t q, _Float16 s) {
  union { uint32_t u[4]; half8 h; } w;
  w.u[0] = dec2(q & 0xFFu);
  w.u[1] = dec2((q >> 8) & 0xFFu);
  w.u[2] = dec2((q >> 16) & 0xFFu);
  w.u[3] = dec2((q >> 24) & 0xFFu);
  half8 sv = {s, s, s, s, s, s, s, s};
  return w.h * sv;
}

// Fused prep: blocks [0,256) -> out = bias broadcast; blocks [256,512) -> A f32->f16.
__global__ void prep_kernel(const floatx4* __restrict__ in4,
                            half4_t* __restrict__ a16,        // may be null
                            const floatx4* __restrict__ bias4,
                            floatx4* __restrict__ out4) {
  int b = blockIdx.x;
  if (b < (M_DIM * N_DIM / 4 / 256)) {
    int idx = b * 256 + threadIdx.x;                 // [0, 65536)
    out4[idx] = bias4[idx & (N_DIM / 4 - 1)];
  } else {
    int idx = (b - (M_DIM * N_DIM / 4 / 256)) * 256 + threadIdx.x;
    floatx4 f = in4[idx];
    half4_t h;
    h[0] = (_Float16)f[0]; h[1] = (_Float16)f[1];
    h[2] = (_Float16)f[2]; h[3] = (_Float16)f[3];
    a16[idx] = h;
  }
}

template <bool F16A>
__global__ __launch_bounds__(256, 4) void fp4_linear_kernel(
    const void*  __restrict__ Av,      // f16 [32][8192] (ws) or f32 (inp)
    const int4*  __restrict__ qw4,     // [N][1024] int4 view of [N, K/2] i32
    const float* __restrict__ scales,  // [8192, 512] f32
    const float* __restrict__ amaxp,   // [1]
    float*       __restrict__ out)     // [32][8192] f32, pre-init'd to bias
{
  __shared__ uint32_t Qs[NPB * QROW];     // 4352 B (packed nibbles)
  __shared__ _Float16 As[M_DIM * AROW];   // 8704 B
  __shared__ float    Ss[NPB * SROW];     // 2304 B   -> 15360 B total

  const int t    = threadIdx.x;
  const int lane = t & 63;
  const int w    = t >> 6;
  const int ks   = blockIdx.x & (KS - 1);
  const int nb   = blockIdx.x >> 3;       // log2(KS)
  const int n0   = nb * NPB;
  const int kb   = ks * KCH;
  const float amax = amaxp[0];

  // Per-block chunk-phase rotation: concurrent blocks walk DIFFERENT 256B
  // k-windows of the 16KB-strided qweight rows -> full HBM channel coverage
  // instead of device-wide lockstep hammering of one narrow column.
  const int phase = nb & (NCHK - 1);

  // Per-thread staging geometry (fixed across chunks)
  const int qr = t >> 4, qc = t & 15;       // Q: 16 rows x 16 int4 per j-step (4 j-steps)
  const int4* qsrc = qw4 + (size_t)(n0 + qr) * QW_ROWI4 + ks * (KCH / 8) + qc;
  const int sr = t >> 2, sh = t & 3;        // S: 64 rows x 4 threads x 2 f32
  const float* ssrc = scales + (size_t)(n0 + sr) * SC_ROW + ks * (KCH / 16) + sh * 2;
  // A f16: 32 rows x 16 half8 per chunk (2 j-steps); f32: 32 rows x 32 float4 (4 j-steps)
  const int ar16 = t >> 4, ac16 = t & 15;
  const _Float16* asrc16 =
      (const _Float16*)Av + (size_t)ar16 * K_DIM + kb + ac16 * 8;
  const int ar32 = t >> 5, ac32 = t & 31;
  const float* asrc32 = (const float*)Av + (size_t)ar32 * K_DIM + kb + ac32 * 4;

  // Staging registers (const-indexed, fully unrolled -> no scratch)
  int4    qreg[4];
  half8   areg16[2];
  floatx4 areg32[4];
  floatx2 sreg;

  // ---------------- preload chunk (phase) ----------------
  {
    const int cc = phase;
#pragma unroll
    for (int j = 0; j < 4; ++j)
      qreg[j] = qsrc[(size_t)j * 16 * QW_ROWI4 + cc * (CHK / 8)];
    if (F16A) {
#pragma unroll
      for (int j = 0; j < 2; ++j)
        areg16[j] = *(const half8*)(asrc16 + (size_t)j * 16 * K_DIM + cc * CHK);
    } else {
#pragma unroll
      for (int j = 0; j < 4; ++j)
        areg32[j] = *(const floatx4*)(asrc32 + (size_t)j * 8 * K_DIM + cc * CHK);
    }
    sreg = *(const floatx2*)(ssrc + cc * (CHK / 16));
  }

  // Compute-side pointers
  const int row  = lane & 15;
  const int quad = lane >> 4;
  const int nloc = w * 16;                 // each wave owns a 16-col strip
  const uint32_t* qAp = &Qs[(nloc + row) * QROW];
  const _Float16* a0p = &As[row * AROW];
  const _Float16* a1p = &As[(row + 16) * AROW];
  const float*    sAp = &Ss[(nloc + row) * SROW];

  floatx4 acc0 = {0.f, 0.f, 0.f, 0.f};
  floatx4 acc1 = {0.f, 0.f, 0.f, 0.f};

  for (int c = 0; c < NCHK; ++c) {
    if (c) __syncthreads();              // previous chunk's LDS fully consumed

    // -------- store staged regs -> LDS --------
#pragma unroll
    for (int j = 0; j < 4; ++j) {
      uint32_t pk = ((uint32_t)qreg[j].x & 0xFFu)
                  | (((uint32_t)qreg[j].y & 0xFFu) << 8)
                  | (((uint32_t)qreg[j].z & 0xFFu) << 16)
                  | (((uint32_t)qreg[j].w & 0xFFu) << 24);
      Qs[(j * 16 + qr) * QROW + qc] = pk;
    }
    if (F16A) {
#pragma unroll
      for (int j = 0; j < 2; ++j)
        *(half8*)&As[(j * 16 + ar16) * AROW + ac16 * 8] = areg16[j];
    } else {
#pragma unroll
      for (int j = 0; j < 4; ++j) {
        floatx4 f = areg32[j];
        half4_t h;
        h[0] = (_Float16)f[0]; h[1] = (_Float16)f[1];
        h[2] = (_Float16)f[2]; h[3] = (_Float16)f[3];
        *(half4_t*)&As[(j * 8 + ar32) * AROW + ac32 * 4] = h;
      }
    }
    {
      float* sd = &Ss[sr * SROW + sh * 2];
      sd[0] = sreg[0] * amax; sd[1] = sreg[1] * amax;
    }
    __syncthreads();

    // -------- issue next chunk's loads (in flight during compute) --------
    if (c + 1 < NCHK) {
      const int cn = (c + 1 + phase) & (NCHK - 1);
#pragma unroll
      for (int j = 0; j < 4; ++j)
        qreg[j] = qsrc[(size_t)j * 16 * QW_ROWI4 + cn * (CHK / 8)];
      if (F16A) {
#pragma unroll
        for (int j = 0; j < 2; ++j)
          areg16[j] = *(const half8*)(asrc16 + (size_t)j * 16 * K_DIM + cn * CHK);
      } else {
#pragma unroll
        for (int j = 0; j < 4; ++j)
          areg32[j] = *(const floatx4*)(asrc32 + (size_t)j * 8 * K_DIM + cn * CHK);
      }
      sreg = *(const floatx2*)(ssrc + cn * (CHK / 16));
    }

    // -------- compute chunk c from LDS (k-window identity irrelevant: sum) --------
#pragma unroll
    for (int it = 0; it < STEPS; ++it) {
      const uint32_t qA = qAp[it * 4 + quad];
      const _Float16 sA = (_Float16)sAp[it * 2 + (quad >> 1)];
      half8 bA = decode8p(qA, sA);
      half8 a0 = *(const half8*)(a0p + it * 32 + quad * 8);
      half8 a1 = *(const half8*)(a1p + it * 32 + quad * 8);
      acc0 = __builtin_amdgcn_mfma_f32_16x16x32_f16(a0, bA, acc0, 0, 0, 0);
      acc1 = __builtin_amdgcn_mfma_f32_16x16x32_f16(a1, bA, acc1, 0, 0, 0);
    }
  }

  // ---- Epilogue: atomic accumulate into out (pre-init'd with bias). ----
  // D fragment: col(n) = lane&15, row(m) = quad*4 + reg.
#pragma unroll
  for (int r = 0; r < 4; ++r) {
    const int m = quad * 4 + r;
    atomicAdd(&out[(size_t)m * N_DIM + n0 + nloc + row], acc0[r]);
    atomicAdd(&out[(size_t)(m + 16) * N_DIM + n0 + nloc + row], acc1[r]);
  }
}

extern "C" void kernel_launch(void* const* d_in, const int* in_sizes, int n_in,
                              void* d_out, int out_size, void* d_ws, size_t ws_size,
                              hipStream_t stream) {
  const float* inp    = (const float*)d_in[0];
  const int4*  qw4    = (const int4*)d_in[1];
  const float* scales = (const float*)d_in[2];
  const float* amaxp  = (const float*)d_in[3];
  const float* bias   = (const float*)d_in[4];
  float* out = (float*)d_out;

  const size_t a16_bytes = (size_t)M_DIM * K_DIM * sizeof(_Float16);  // 512 KB
  const int init_blocks = M_DIM * N_DIM / 4 / 256;   // 256
  const int conv_blocks = M_DIM * K_DIM / 4 / 256;   // 256

  if (ws_size >= a16_bytes) {
    _Float16* Af16 = (_Float16*)d_ws;
    prep_kernel<<<init_blocks + conv_blocks, 256, 0, stream>>>(
        (const floatx4*)inp, (half4_t*)Af16, (const floatx4*)bias,
        (floatx4*)out);
    fp4_linear_kernel<true><<<MAIN_BLOCKS, 256, 0, stream>>>(
        Af16, qw4, scales, amaxp, out);
  } else {
    prep_kernel<<<init_blocks, 256, 0, stream>>>(
        nullptr, nullptr, (const floatx4*)bias, (floatx4*)out);
    fp4_linear_kernel<false><<<MAIN_BLOCKS, 256, 0, stream>>>(
        inp, qw4, scales, amaxp, out);
  }
}

// Round 4
// 214.207 us; speedup vs baseline: 1.0093x; 1.0093x over previous
//
#include <hip/hip_runtime.h>
#include <hip/hip_bf16.h>

// Problem dims (fixed by reference setup_inputs)
#define M_DIM 32
#define K_DIM 8192
#define N_DIM 8192
#define KS 8                         // k-split slices (atomic adds per output elem)
#define KCH (K_DIM / KS)             // 1024 k per block
#define CHK 128                      // k per pipelined chunk
#define NCHK (KCH / CHK)             // 8 chunks
#define STEPS (CHK / 32)             // 4 MFMA k-steps per chunk
#define NPB 64                       // n-cols per block
#define MAIN_BLOCKS ((N_DIM / NPB) * KS)  // 1024

#define QW_ROWI4 (K_DIM / 8)         // 1024 int4 per qweight row
#define SC_ROW (K_DIM / 16)          // 512 f32 per scales row

// LDS strides (padding class proven earlier; conflicts <=2-way = free)
#define QROW 17                      // packed dwords per Q row (16 + 1)
#define AROW 136                     // f16 per A row (128 + 8)
#define SROW 9                       // f32 per S row (8 + 1)

typedef _Float16 half8   __attribute__((ext_vector_type(8)));
typedef _Float16 half4_t __attribute__((ext_vector_type(4)));
typedef float    floatx4 __attribute__((ext_vector_type(4)));
typedef float    floatx2 __attribute__((ext_vector_type(2)));

// ---- Proven E2M1 bit-decode (absmax 2.0 pedigree) ----
__device__ __forceinline__ uint32_t dec2(uint32_t b) {
  uint32_t c0 = b & 0xFu, c1 = (b >> 4) & 0xFu;
  uint32_t m0 = c0 & 7u, m1 = c1 & 7u;
  uint32_t t0 = min(28u * m0, m0 + 28u);
  uint32_t t1 = min(28u * m1, m1 + 28u);
  return (t0 << 9) | ((c0 & 8u) << 12)
       | (t1 << 25) | ((c1 & 8u) << 28);
}

// Packed dword (4 payload bytes = 8 fp4 along k) -> 8 f16, times f16 scale.
__device__ __forceinline__ half8 decode8p(uint32_t q, _Float16 s) {
  union { uint32_t u[4]; half8 h; } w;
  w.u[0] = dec2(q & 0xFFu);
  w.u[1] = dec2((q >> 8) & 0xFFu);
  w.u[2] = dec2((q >> 16) & 0xFFu);
  w.u[3] = dec2((q >> 24) & 0xFFu);
  half8 sv = {s, s, s, s, s, s, s, s};
  return w.h * sv;
}

// Fused prep: blocks [0,256) -> out = bias broadcast; blocks [256,512) -> A f32->f16.
__global__ void prep_kernel(const floatx4* __restrict__ in4,
                            half4_t* __restrict__ a16,        // may be null
                            const floatx4* __restrict__ bias4,
                            floatx4* __restrict__ out4) {
  int b = blockIdx.x;
  if (b < (M_DIM * N_DIM / 4 / 256)) {
    int idx = b * 256 + threadIdx.x;                 // [0, 65536)
    out4[idx] = bias4[idx & (N_DIM / 4 - 1)];
  } else {
    int idx = (b - (M_DIM * N_DIM / 4 / 256)) * 256 + threadIdx.x;
    floatx4 f = in4[idx];
    half4_t h;
    h[0] = (_Float16)f[0]; h[1] = (_Float16)f[1];
    h[2] = (_Float16)f[2]; h[3] = (_Float16)f[3];
    a16[idx] = h;
  }
}

template <bool F16A>
__global__ __launch_bounds__(256, 4) void fp4_linear_kernel(
    const void*  __restrict__ Av,      // f16 [32][8192] (ws) or f32 (inp)
    const int4*  __restrict__ qw4,     // [N][1024] int4 view of [N, K/2] i32
    const float* __restrict__ scales,  // [8192, 512] f32
    const float* __restrict__ amaxp,   // [1]
    float*       __restrict__ out)     // [32][8192] f32, pre-init'd to bias
{
  __shared__ uint32_t Qs[NPB * QROW];     // 4352 B (packed nibbles)
  __shared__ _Float16 As[M_DIM * AROW];   // 8704 B
  __shared__ float    Ss[NPB * SROW];     // 2304 B   -> 15360 B total

  const int t    = threadIdx.x;
  const int lane = t & 63;
  const int w    = t >> 6;
  const int ks   = blockIdx.x & (KS - 1);
  const int nb   = blockIdx.x >> 3;       // log2(KS)
  const int n0   = nb * NPB;
  const int kb   = ks * KCH;
  const float amax = amaxp[0];

  // Per-thread staging geometry (fixed across chunks)
  const int qr = t >> 4, qc = t & 15;       // Q: 16 rows x 16 int4 per j-step (4 j-steps)
  const int4* qsrc = qw4 + (size_t)(n0 + qr) * QW_ROWI4 + ks * (KCH / 8) + qc;
  const int sr = t >> 2, sh = t & 3;        // S: 64 rows x 4 threads x 2 f32
  const float* ssrc = scales + (size_t)(n0 + sr) * SC_ROW + ks * (KCH / 16) + sh * 2;
  // A f16: 32 rows x 16 half8 per chunk (2 j-steps); f32: 32 rows x 32 float4 (4 j-steps)
  const int ar16 = t >> 4, ac16 = t & 15;
  const _Float16* asrc16 =
      (const _Float16*)Av + (size_t)ar16 * K_DIM + kb + ac16 * 8;
  const int ar32 = t >> 5, ac32 = t & 31;
  const float* asrc32 = (const float*)Av + (size_t)ar32 * K_DIM + kb + ac32 * 4;

  // Depth-2 register ping-pong: loads for chunk c+1 are issued at the TOP of
  // chunk c's iteration (before barriers/pack), so load->use distance covers a
  // full chunk period (~latency) instead of only the ~350cy compute phase.
  int4    qregA[4], qregB[4];
  half8   aregA16[2], aregB16[2];
  floatx4 aregA32[4], aregB32[4];
  floatx2 sregA, sregB;

#define ISSUE_A(CO)                                                         \
  if ((CO) < NCHK) {                                                        \
    _Pragma("unroll")                                                       \
    for (int j = 0; j < 4; ++j)                                             \
      qregA[j] = qsrc[(size_t)j * 16 * QW_ROWI4 + (CO) * (CHK / 8)];        \
    if (F16A) {                                                             \
      _Pragma("unroll")                                                     \
      for (int j = 0; j < 2; ++j)                                           \
        aregA16[j] = *(const half8*)(asrc16 + (size_t)j * 16 * K_DIM + (CO) * CHK); \
    } else {                                                                \
      _Pragma("unroll")                                                     \
      for (int j = 0; j < 4; ++j)                                           \
        aregA32[j] = *(const floatx4*)(asrc32 + (size_t)j * 8 * K_DIM + (CO) * CHK); \
    }                                                                       \
    sregA = *(const floatx2*)(ssrc + (CO) * (CHK / 16));                    \
  }

#define ISSUE_B(CO)                                                         \
  if ((CO) < NCHK) {                                                        \
    _Pragma("unroll")                                                       \
    for (int j = 0; j < 4; ++j)                                             \
      qregB[j] = qsrc[(size_t)j * 16 * QW_ROWI4 + (CO) * (CHK / 8)];        \
    if (F16A) {                                                             \
      _Pragma("unroll")                                                     \
      for (int j = 0; j < 2; ++j)                                           \
        aregB16[j] = *(const half8*)(asrc16 + (size_t)j * 16 * K_DIM + (CO) * CHK); \
    } else {                                                                \
      _Pragma("unroll")                                                     \
      for (int j = 0; j < 4; ++j)                                           \
        aregB32[j] = *(const floatx4*)(asrc32 + (size_t)j * 8 * K_DIM + (CO) * CHK); \
    }                                                                       \
    sregB = *(const floatx2*)(ssrc + (CO) * (CHK / 16));                    \
  }

#define STORE_LDS(QR, AR16, AR32, SR)                                       \
  {                                                                         \
    _Pragma("unroll")                                                       \
    for (int j = 0; j < 4; ++j) {                                           \
      uint32_t pk = ((uint32_t)QR[j].x & 0xFFu)                             \
                  | (((uint32_t)QR[j].y & 0xFFu) << 8)                      \
                  | (((uint32_t)QR[j].z & 0xFFu) << 16)                     \
                  | (((uint32_t)QR[j].w & 0xFFu) << 24);                    \
      Qs[(j * 16 + qr) * QROW + qc] = pk;                                   \
    }                                                                       \
    if (F16A) {                                                             \
      _Pragma("unroll")                                                     \
      for (int j = 0; j < 2; ++j)                                           \
        *(half8*)&As[(j * 16 + ar16) * AROW + ac16 * 8] = AR16[j];          \
    } else {                                                                \
      _Pragma("unroll")                                                     \
      for (int j = 0; j < 4; ++j) {                                         \
        floatx4 f = AR32[j];                                                \
        half4_t h;                                                          \
        h[0] = (_Float16)f[0]; h[1] = (_Float16)f[1];                       \
        h[2] = (_Float16)f[2]; h[3] = (_Float16)f[3];                       \
        *(half4_t*)&As[(j * 8 + ar32) * AROW + ac32 * 4] = h;               \
      }                                                                     \
    }                                                                       \
    {                                                                       \
      float* sd = &Ss[sr * SROW + sh * 2];                                  \
      sd[0] = SR[0] * amax; sd[1] = SR[1] * amax;                           \
    }                                                                       \
  }

  // Compute-side pointers
  const int row  = lane & 15;
  const int quad = lane >> 4;
  const int nloc = w * 16;                 // each wave owns a 16-col strip
  const uint32_t* qAp = &Qs[(nloc + row) * QROW];
  const _Float16* a0p = &As[row * AROW];
  const _Float16* a1p = &As[(row + 16) * AROW];
  const float*    sAp = &Ss[(nloc + row) * SROW];

  floatx4 acc0 = {0.f, 0.f, 0.f, 0.f};
  floatx4 acc1 = {0.f, 0.f, 0.f, 0.f};

#define COMPUTE_CHUNK                                                       \
  {                                                                         \
    _Pragma("unroll")                                                       \
    for (int it = 0; it < STEPS; ++it) {                                    \
      const uint32_t qA = qAp[it * 4 + quad];                               \
      const _Float16 sA = (_Float16)sAp[it * 2 + (quad >> 1)];              \
      half8 bA = decode8p(qA, sA);                                          \
      half8 a0 = *(const half8*)(a0p + it * 32 + quad * 8);                 \
      half8 a1 = *(const half8*)(a1p + it * 32 + quad * 8);                 \
      acc0 = __builtin_amdgcn_mfma_f32_16x16x32_f16(a0, bA, acc0, 0, 0, 0); \
      acc1 = __builtin_amdgcn_mfma_f32_16x16x32_f16(a1, bA, acc1, 0, 0, 0); \
    }                                                                       \
  }

  // ---------------- preload chunk 0 into set A ----------------
  ISSUE_A(0);

#pragma unroll
  for (int cc = 0; cc < NCHK / 2; ++cc) {
    const int e = 2 * cc;
    // -------- chunk e (data in A) --------
    ISSUE_B(e + 1);                 // issued a full chunk before its pack
    if (e) __syncthreads();         // previous chunk's LDS fully consumed
    STORE_LDS(qregA, aregA16, aregA32, sregA);  // waits only on A (old)
    __syncthreads();
    COMPUTE_CHUNK;
    // -------- chunk e+1 (data in B) --------
    ISSUE_A(e + 2);
    __syncthreads();
    STORE_LDS(qregB, aregB16, aregB32, sregB);
    __syncthreads();
    COMPUTE_CHUNK;
  }

#undef ISSUE_A
#undef ISSUE_B
#undef STORE_LDS
#undef COMPUTE_CHUNK

  // ---- Epilogue: atomic accumulate into out (pre-init'd with bias). ----
  // D fragment: col(n) = lane&15, row(m) = quad*4 + reg.
#pragma unroll
  for (int r = 0; r < 4; ++r) {
    const int m = quad * 4 + r;
    atomicAdd(&out[(size_t)m * N_DIM + n0 + nloc + row], acc0[r]);
    atomicAdd(&out[(size_t)(m + 16) * N_DIM + n0 + nloc + row], acc1[r]);
  }
}

extern "C" void kernel_launch(void* const* d_in, const int* in_sizes, int n_in,
                              void* d_out, int out_size, void* d_ws, size_t ws_size,
                              hipStream_t stream) {
  const float* inp    = (const float*)d_in[0];
  const int4*  qw4    = (const int4*)d_in[1];
  const float* scales = (const float*)d_in[2];
  const float* amaxp  = (const float*)d_in[3];
  const float* bias   = (const float*)d_in[4];
  float* out = (float*)d_out;

  const size_t a16_bytes = (size_t)M_DIM * K_DIM * sizeof(_Float16);  // 512 KB
  const int init_blocks = M_DIM * N_DIM / 4 / 256;   // 256
  const int conv_blocks = M_DIM * K_DIM / 4 / 256;   // 256

  if (ws_size >= a16_bytes) {
    _Float16* Af16 = (_Float16*)d_ws;
    prep_kernel<<<init_blocks + conv_blocks, 256, 0, stream>>>(
        (const floatx4*)inp, (half4_t*)Af16, (const floatx4*)bias,
        (floatx4*)out);
    fp4_linear_kernel<true><<<MAIN_BLOCKS, 256, 0, stream>>>(
        Af16, qw4, scales, amaxp, out);
  } else {
    prep_kernel<<<init_blocks, 256, 0, stream>>>(
        nullptr, nullptr, (const floatx4*)bias, (floatx4*)out);
    fp4_linear_kernel<false><<<MAIN_BLOCKS, 256, 0, stream>>>(
        inp, qw4, scales, amaxp, out);
  }
}